// Round 11
// baseline (168.791 us; speedup 1.0000x reference)
//
#include <hip/hip_runtime.h>
#include <math.h>

#define B_ 16
#define M_ 1024
#define N_ 1024
#define D_ 512
#define MP1 1025
#define NP1 1025
#define NUM_SINK 8
#define BK 64
#define SSTR 1024        // fp16 S row stride (elements) — interior only
#define VSTR 1028        // v stride (floats), 16B-aligned
#define NCHK 16          // ps chunks (64 rows each)
#define PSTOT (16 * B_ * 1025)   // floats per ps buffer
// log(1/2048), log(1/2)
#define LOG_NORM (-7.6246189861593985f)
#define LOG_HALF (-0.6931471805599453f)

typedef __attribute__((ext_vector_type(8))) short bf16x8;
typedef __attribute__((ext_vector_type(4))) float f32x4;
typedef __attribute__((ext_vector_type(8))) _Float16 h16x8;

__device__ inline short f2bf(float x) {
    unsigned u = __builtin_bit_cast(unsigned, x);
    u = (u + 0x7FFFu + ((u >> 16) & 1u)) >> 16;
    return (short)u;
}

__device__ inline void gload16(const void* g, void* l) {
    __builtin_amdgcn_global_load_lds(
        (const __attribute__((address_space(1))) unsigned int*)g,
        (__attribute__((address_space(3))) unsigned int*)l, 16, 0, 0);
}

// ---------------- norms: one wave per feature row ----------------
template<bool PRE>
__global__ __launch_bounds__(256) void norms_kernel_t(
    const float* __restrict__ tf, const float* __restrict__ df,
    float* __restrict__ inv1, float* __restrict__ inv2,
    unsigned short* __restrict__ tfh, unsigned short* __restrict__ dfh)
{
    int w = (blockIdx.x * 256 + threadIdx.x) >> 6;
    int lane = threadIdx.x & 63;
    if (w >= B_ * 2048) return;
    int b = w >> 11;
    int rr = w & 2047;
    const float* src;
    float* dst = nullptr;
    unsigned short* dsth = nullptr;
    if (rr < M_) { src = tf + ((size_t)b * M_ + rr) * D_;
                   if (!PRE) dst = inv1 + b * M_ + rr;
                   if (PRE)  dsth = tfh + ((size_t)b * M_ + rr) * D_; }
    else         { src = df + ((size_t)b * N_ + (rr - M_)) * D_;
                   if (!PRE) dst = inv2 + b * N_ + (rr - M_);
                   if (PRE)  dsth = dfh + ((size_t)b * N_ + (rr - M_)) * D_; }
    float4 x = *(const float4*)(src + lane * 4);
    float4 y = *(const float4*)(src + 256 + lane * 4);
    float ss = x.x*x.x + x.y*x.y + x.z*x.z + x.w*x.w
             + y.x*y.x + y.y*y.y + y.z*y.z + y.w*y.w;
    #pragma unroll
    for (int o = 32; o; o >>= 1) ss += __shfl_xor(ss, o);
    if (PRE) {
        float rn = rsqrtf(ss);
        ushort4 hx, hy;
        hx.x = (unsigned short)f2bf(x.x*rn); hx.y = (unsigned short)f2bf(x.y*rn);
        hx.z = (unsigned short)f2bf(x.z*rn); hx.w = (unsigned short)f2bf(x.w*rn);
        hy.x = (unsigned short)f2bf(y.x*rn); hy.y = (unsigned short)f2bf(y.y*rn);
        hy.z = (unsigned short)f2bf(y.z*rn); hy.w = (unsigned short)f2bf(y.w*rn);
        *(ushort4*)(dsth + lane * 4) = hx;
        *(ushort4*)(dsth + 256 + lane * 4) = hy;
    } else {
        if (lane == 0) *dst = 1.0f / sqrtf(ss);
    }
}

// ---------------- MFMA GEMM + epilogue: S = (cos*mask - 1)/lambda ----------------
template<int MODE>
__global__ __launch_bounds__(256) void gemm_s_kernel(
    const void* __restrict__ A, const void* __restrict__ Bm,
    const float* __restrict__ tl, const float* __restrict__ dl,
    const float* __restrict__ inv1, const float* __restrict__ inv2,
    const float* __restrict__ eps_p, void* __restrict__ Sout)
{
    __shared__ __align__(16) unsigned short As[2][128 * BK];
    __shared__ __align__(16) unsigned short Bs[2][128 * BK];

    int flat = blockIdx.x;
    int swz = (flat & 7) * 128 + (flat >> 3);
    int jb = swz & 7, ib = (swz >> 3) & 7;
    int b  = swz >> 6;
    int i0 = ib * 128;
    int j0 = jb * 128;

    int tid  = threadIdx.x;
    int lane = tid & 63;
    int w    = tid >> 6;
    int wm   = w >> 1, wn = w & 1;

    f32x4 acc[4][4] = {};

    if constexpr (MODE == 2) {
        const unsigned short* Ah = (const unsigned short*)A  + (size_t)b * M_ * D_;
        const unsigned short* Bh = (const unsigned short*)Bm + (size_t)b * N_ * D_;
        int gcol = ((lane & 7) ^ (lane >> 3)) << 3;
        int rloc = lane >> 3;

        auto stage = [&](int k0, int buf) {
            #pragma unroll
            for (int c = 0; c < 4; ++c) {
                int r = (w * 4 + c) * 8 + rloc;
                gload16(Ah + (size_t)(i0 + r) * D_ + k0 + gcol,
                        (char*)As[buf] + (w * 4 + c) * 1024 + lane * 16);
                gload16(Bh + (size_t)(j0 + r) * D_ + k0 + gcol,
                        (char*)Bs[buf] + (w * 4 + c) * 1024 + lane * 16);
            }
        };

        stage(0, 0);
        __syncthreads();
        int cur = 0;
        for (int t = 0; t < D_ / BK; ++t) {
            if (t < D_ / BK - 1) stage((t + 1) * BK, cur ^ 1);
            #pragma unroll
            for (int ks = 0; ks < 2; ++ks) {
                int kb = ks * 64 + ((lane >> 4) << 4);
                bf16x8 af[4], bfr[4];
                #pragma unroll
                for (int m = 0; m < 4; ++m) {
                    int ra = wm * 64 + m * 16 + (lane & 15);
                    af[m] = *(const bf16x8*)((const char*)As[cur] + ra * 128 + (kb ^ ((ra & 7) << 4)));
                    int rb = wn * 64 + m * 16 + (lane & 15);
                    bfr[m] = *(const bf16x8*)((const char*)Bs[cur] + rb * 128 + (kb ^ ((rb & 7) << 4)));
                }
                #pragma unroll
                for (int m = 0; m < 4; ++m)
                    #pragma unroll
                    for (int n = 0; n < 4; ++n)
                        acc[m][n] = __builtin_amdgcn_mfma_f32_16x16x32_bf16(af[m], bfr[n], acc[m][n], 0, 0, 0);
            }
            __syncthreads();
            cur ^= 1;
        }
    } else {
        const float* Ab = (const float*)A  + (size_t)b * M_ * D_;
        const float* Bb = (const float*)Bm + (size_t)b * N_ * D_;
        int seg   = tid & 7;
        int rbase = tid >> 3;
        for (int k0 = 0; k0 < D_; k0 += BK) {
            #pragma unroll
            for (int rr = 0; rr < 4; ++rr) {
                int r = rbase + rr * 32;
                int colx = (seg * 16) ^ ((r & 7) << 4);
                {
                    const float* pa = Ab + (size_t)(i0 + r) * D_ + k0 + seg * 8;
                    float4 a0 = *(const float4*)pa;
                    float4 a1 = *(const float4*)(pa + 4);
                    bf16x8 hv;
                    hv[0] = f2bf(a0.x); hv[1] = f2bf(a0.y); hv[2] = f2bf(a0.z); hv[3] = f2bf(a0.w);
                    hv[4] = f2bf(a1.x); hv[5] = f2bf(a1.y); hv[6] = f2bf(a1.z); hv[7] = f2bf(a1.w);
                    *(bf16x8*)((char*)As[0] + r * 128 + colx) = hv;
                }
                {
                    const float* pb = Bb + (size_t)(j0 + r) * D_ + k0 + seg * 8;
                    float4 b0 = *(const float4*)pb;
                    float4 b1 = *(const float4*)(pb + 4);
                    bf16x8 hv;
                    hv[0] = f2bf(b0.x); hv[1] = f2bf(b0.y); hv[2] = f2bf(b0.z); hv[3] = f2bf(b0.w);
                    hv[4] = f2bf(b1.x); hv[5] = f2bf(b1.y); hv[6] = f2bf(b1.z); hv[7] = f2bf(b1.w);
                    *(bf16x8*)((char*)Bs[0] + r * 128 + colx) = hv;
                }
            }
            __syncthreads();
            #pragma unroll
            for (int ks = 0; ks < 2; ++ks) {
                int kb = ks * 64 + ((lane >> 4) << 4);
                bf16x8 af[4], bfr[4];
                #pragma unroll
                for (int m = 0; m < 4; ++m) {
                    int ra = wm * 64 + m * 16 + (lane & 15);
                    af[m] = *(const bf16x8*)((const char*)As[0] + ra * 128 + (kb ^ ((ra & 7) << 4)));
                    int rb = wn * 64 + m * 16 + (lane & 15);
                    bfr[m] = *(const bf16x8*)((const char*)Bs[0] + rb * 128 + (kb ^ ((rb & 7) << 4)));
                }
                #pragma unroll
                for (int m = 0; m < 4; ++m)
                    #pragma unroll
                    for (int n = 0; n < 4; ++n)
                        acc[m][n] = __builtin_amdgcn_mfma_f32_16x16x32_bf16(af[m], bfr[n], acc[m][n], 0, 0, 0);
            }
            __syncthreads();
        }
    }

    float lam = __expf(eps_p[0]) + 0.03f;
    float inv_lam = 1.0f / lam;
    int crow0 = i0 + wm * 64;
    int ccol0 = j0 + wn * 64;
    int rlane = lane >> 4;
    int clane = lane & 15;

    float invb_[4], dlx_[4], dly_[4];
    #pragma unroll
    for (int n = 0; n < 4; ++n) {
        int j = ccol0 + n * 16 + clane;
        if (MODE != 2) invb_[n] = inv2[b * N_ + j];
        dlx_[n]  = dl[((size_t)b * N_ + j) * 2 + 0];
        dly_[n]  = dl[((size_t)b * N_ + j) * 2 + 1];
    }
    #pragma unroll
    for (int m = 0; m < 4; ++m) {
        #pragma unroll
        for (int reg = 0; reg < 4; ++reg) {
            int i = crow0 + m * 16 + rlane * 4 + reg;
            float inva = (MODE != 2) ? inv1[b * M_ + i] : 1.0f;
            float tlx  = tl[((size_t)b * M_ + i) * 2 + 0];
            float tly  = tl[((size_t)b * M_ + i) * 2 + 1];
            #pragma unroll
            for (int n = 0; n < 4; ++n) {
                float cosv = (MODE == 2) ? acc[m][n][reg]
                                         : acc[m][n][reg] * inva * invb_[n];
                float dx = tlx - dlx_[n];
                float dy = tly - dly_[n];
                float mi = (fmaf(dx, dx, dy * dy) <= 0.09f) ? inv_lam : 0.0f;
                float val = fmaf(cosv, mi, -inv_lam);
                int col = ccol0 + n * 16 + clane;
                if (MODE >= 1) {
                    _Float16* Srow = (_Float16*)Sout + ((size_t)b * M_ + i) * SSTR;
                    Srow[col] = (_Float16)val;
                } else {
                    float* Srow = (float*)Sout + ((size_t)b * MP1 + i) * NP1;
                    Srow[col] = val;
                }
            }
        }
    }
}

// ================= fused v-update + row pass + column partials =================
// F(it): reads v,ps at parity it&1; writes v,ps at parity (it+1)&1.
// Phase A: each block recomputes v_cur (redundantly) into LDS from prev partials.
// Phase B: 64-row pass (4 waves x 16 preloaded rows) producing this iter's partials.
__global__ __launch_bounds__(256, 1) void rowcolv64(
    const _Float16* __restrict__ Sh, float* __restrict__ vbuf,
    float* __restrict__ psbuf,
    const float* __restrict__ alpha_p, const float* __restrict__ eps_p,
    int it)
{
    int blk = blockIdx.x;           // 0..255
    int b = blk >> 4, k = blk & 15;
    int tid = threadIdx.x, lane = tid & 63, w = tid >> 6;

    __shared__ float red[4][64][17];   // stride-17: conflict-free
    __shared__ float vsh[1025];
    __shared__ float wred[4];

    const _Float16* Sb = Sh + ((size_t)b << 20);
    int rbase = k * 64 + w * 16;

    // issue S preloads early — latency hides under phase A
    h16x8 h0[16], h1[16];
    #pragma unroll
    for (int rr = 0; rr < 16; ++rr) {
        const _Float16* row = Sb + (size_t)(rbase + rr) * SSTR;
        h0[rr] = *(const h16x8*)(row + lane * 8);
        h1[rr] = *(const h16x8*)(row + 512 + lane * 8);
    }

    int rp = it & 1, wp = rp ^ 1;

    // ---- phase A: v_cur -> vsh ----
    if (it == 0) {
        for (int j = tid; j < 1025; j += 256) vsh[j] = 0.f;
    } else {
        const float* vin = vbuf + (size_t)rp * (B_ * VSTR) + (size_t)b * VSTR;
        const float* pin = psbuf + (size_t)rp * PSTOT + (size_t)b * 1025;
        float vp[4]; float vp4 = 0.f;
        float evs = 0.f;
        #pragma unroll
        for (int q = 0; q < 4; ++q) { vp[q] = vin[tid + q * 256]; evs += __expf(vp[q]); }
        if (tid == 0) { vp4 = vin[1024]; evs += __expf(vp4); }
        #pragma unroll
        for (int o = 32; o; o >>= 1) evs += __shfl_xor(evs, o);
        if (lane == 0) wred[w] = evs;
        __syncthreads();
        float Sev = wred[0] + wred[1] + wred[2] + wred[3];
        #pragma unroll
        for (int q = 0; q < 4; ++q) {
            int j = tid + q * 256;
            float cs = 0.f;
            #pragma unroll
            for (int c = 0; c < NCHK; ++c) cs += pin[(size_t)c * (B_ * 1025) + j];
            cs += 0.5f * __expf(vp[q]) / Sev;
            vsh[j] = vp[q] + LOG_NORM - __logf(cs);
        }
        if (tid == 0) {
            float cs = 0.f;
            #pragma unroll
            for (int c = 0; c < NCHK; ++c) cs += pin[(size_t)c * (B_ * 1025) + 1024];
            cs += 0.5f * __expf(vp4) / Sev;
            vsh[1024] = vp4 + LOG_HALF - __logf(cs);
        }
    }
    __syncthreads();

    // republish v_cur for the next dispatch (one block per batch)
    if (k == 0) {
        float* vout = vbuf + (size_t)wp * (B_ * VSTR) + (size_t)b * VSTR;
        for (int j = tid; j < 1025; j += 256) vout[j] = vsh[j];
    }

    // ---- phase B: row pass ----
    float vreg[16];
    #pragma unroll
    for (int e = 0; e < 8; ++e) {
        vreg[e]     = vsh[lane * 8 + e];
        vreg[8 + e] = vsh[512 + lane * 8 + e];
    }
    float lam = __expf(eps_p[0]) + 0.03f;
    float s_a = (alpha_p[0] - 1.0f) / lam;
    float et16c = __expf(s_a + vsh[1024]);

    float creg[16] = {};
    float sum_scale = 0.f;

    #pragma unroll
    for (int rr = 0; rr < 16; ++rr) {
        float et[16];
        float rs = 0.f;
        #pragma unroll
        for (int e = 0; e < 8; ++e) { et[e] = __expf((float)h0[rr][e] + vreg[e]); rs += et[e]; }
        #pragma unroll
        for (int e = 0; e < 8; ++e) { et[8+e] = __expf((float)h1[rr][e] + vreg[8+e]); rs += et[8+e]; }
        #pragma unroll
        for (int o = 32; o; o >>= 1) rs += __shfl_xor(rs, o);
        rs += et16c;
        float scale = (1.0f / 2048.0f) / rs;
        #pragma unroll
        for (int e = 0; e < 16; ++e) creg[e] += et[e] * scale;
        sum_scale += scale;
    }

    #pragma unroll
    for (int e = 0; e < 16; ++e) red[w][lane][e] = creg[e];
    if (lane == 0) red[w][0][16] = sum_scale;
    __syncthreads();

    float* pso = psbuf + (size_t)wp * PSTOT + (size_t)(k * B_ + b) * 1025;
    for (int j = tid; j < 1024; j += 256) {
        int lane_j = (j & 511) >> 3;
        int e_j    = ((j >> 9) << 3) | (j & 7);
        pso[j] = red[0][lane_j][e_j] + red[1][lane_j][e_j]
               + red[2][lane_j][e_j] + red[3][lane_j][e_j];
    }
    if (tid == 0)
        pso[1024] = et16c * (red[0][0][16] + red[1][0][16] + red[2][0][16] + red[3][0][16]);
}

// ================= fused final: v_8 recompute + output write =================
// blocks <512: interior rows.  blocks 512..527: dustbin row (one block per batch).
__global__ __launch_bounds__(256) void finalv(
    const _Float16* __restrict__ Sh, const float* __restrict__ vbuf,
    const float* __restrict__ psbuf,
    const float* __restrict__ alpha_p, const float* __restrict__ eps_p,
    float* __restrict__ out)
{
    int blk = blockIdx.x;
    bool dust = blk >= 512;
    int b = dust ? (blk - 512) : (blk >> 5);
    int k = blk & 31;
    int tid = threadIdx.x, lane = tid & 63, w = tid >> 6;

    __shared__ float vsh[1025];
    __shared__ float wred[4];

    const int rp = NUM_SINK & 1;   // = 0: F(7) wrote parity 0
    // ---- phase A: v_8 -> vsh ----
    {
        const float* vin = vbuf + (size_t)rp * (B_ * VSTR) + (size_t)b * VSTR;
        const float* pin = psbuf + (size_t)rp * PSTOT + (size_t)b * 1025;
        float vp[4]; float vp4 = 0.f;
        float evs = 0.f;
        #pragma unroll
        for (int q = 0; q < 4; ++q) { vp[q] = vin[tid + q * 256]; evs += __expf(vp[q]); }
        if (tid == 0) { vp4 = vin[1024]; evs += __expf(vp4); }
        #pragma unroll
        for (int o = 32; o; o >>= 1) evs += __shfl_xor(evs, o);
        if (lane == 0) wred[w] = evs;
        __syncthreads();
        float Sev = wred[0] + wred[1] + wred[2] + wred[3];
        #pragma unroll
        for (int q = 0; q < 4; ++q) {
            int j = tid + q * 256;
            float cs = 0.f;
            #pragma unroll
            for (int c = 0; c < NCHK; ++c) cs += pin[(size_t)c * (B_ * 1025) + j];
            cs += 0.5f * __expf(vp[q]) / Sev;
            vsh[j] = vp[q] + LOG_NORM - __logf(cs);
        }
        if (tid == 0) {
            float cs = 0.f;
            #pragma unroll
            for (int c = 0; c < NCHK; ++c) cs += pin[(size_t)c * (B_ * 1025) + 1024];
            cs += 0.5f * __expf(vp4) / Sev;
            vsh[1024] = vp4 + LOG_HALF - __logf(cs);
        }
    }
    __syncthreads();

    if (dust) {
        float evs = 0.f;
        for (int j = tid; j < 1025; j += 256) evs += __expf(vsh[j]);
        #pragma unroll
        for (int o = 32; o; o >>= 1) evs += __shfl_xor(evs, o);
        if (lane == 0) wred[w] = evs;
        __syncthreads();
        float Sev8 = wred[0] + wred[1] + wred[2] + wred[3];
        float* orow = out + ((size_t)b * MP1 + 1024) * NP1;
        for (int j = tid; j < 1025; j += 256)
            orow[j] = __expf(vsh[j]) * 1024.0f / Sev8;
        return;
    }

    float vreg[16];
    #pragma unroll
    for (int e = 0; e < 8; ++e) {
        vreg[e]     = vsh[lane * 8 + e];
        vreg[8 + e] = vsh[512 + lane * 8 + e];
    }
    float lam = __expf(eps_p[0]) + 0.03f;
    float s_a = (alpha_p[0] - 1.0f) / lam;
    float et16c = __expf(s_a + vsh[1024]);

    const _Float16* Sb = Sh + ((size_t)b << 20);
    int rbase = k * 32 + w * 8;

    #pragma unroll
    for (int g = 0; g < 2; ++g) {
        h16x8 h0[4], h1[4];
        #pragma unroll
        for (int rr = 0; rr < 4; ++rr) {
            const _Float16* row = Sb + (size_t)(rbase + g * 4 + rr) * SSTR;
            h0[rr] = *(const h16x8*)(row + lane * 8);
            h1[rr] = *(const h16x8*)(row + 512 + lane * 8);
        }
        #pragma unroll
        for (int rr = 0; rr < 4; ++rr) {
            int r = rbase + g * 4 + rr;
            float et[16];
            float rs = 0.f;
            #pragma unroll
            for (int e = 0; e < 8; ++e) { et[e] = __expf((float)h0[rr][e] + vreg[e]); rs += et[e]; }
            #pragma unroll
            for (int e = 0; e < 8; ++e) { et[8+e] = __expf((float)h1[rr][e] + vreg[8+e]); rs += et[8+e]; }
            #pragma unroll
            for (int o = 32; o; o >>= 1) rs += __shfl_xor(rs, o);
            rs += et16c;
            float sc = 1.0f / rs;
            float* orow = out + ((size_t)b * MP1 + r) * NP1;
            float4 o0 = {et[0]*sc,  et[1]*sc,  et[2]*sc,  et[3]*sc};
            float4 o1 = {et[4]*sc,  et[5]*sc,  et[6]*sc,  et[7]*sc};
            float4 o2 = {et[8]*sc,  et[9]*sc,  et[10]*sc, et[11]*sc};
            float4 o3 = {et[12]*sc, et[13]*sc, et[14]*sc, et[15]*sc};
            *(float4*)(orow + lane * 8)           = o0;
            *(float4*)(orow + lane * 8 + 4)       = o1;
            *(float4*)(orow + 512 + lane * 8)     = o2;
            *(float4*)(orow + 512 + lane * 8 + 4) = o3;
            if (lane == 0) orow[1024] = et16c * sc;
        }
    }
}

// ================= fp32 fallback kernels (tier 3, S in d_out) =================

__global__ __launch_bounds__(256) void fill_edges_f32(
    float* __restrict__ Sout, const float* __restrict__ alpha_p, const float* __restrict__ eps_p)
{
    int t = blockIdx.x * 256 + threadIdx.x;
    if (t >= B_ * (NP1 + M_)) return;
    int b = t / (NP1 + M_), r = t % (NP1 + M_);
    float lam = expf(eps_p[0]) + 0.03f;
    float s = (alpha_p[0] - 1.0f) / lam;
    size_t idx;
    if (r < NP1) idx = ((size_t)b * MP1 + M_) * NP1 + r;
    else         idx = ((size_t)b * MP1 + (r - NP1)) * NP1 + N_;
    Sout[idx] = s;
}

__global__ __launch_bounds__(256) void row_pass_kernel(
    const float* __restrict__ S, const float* __restrict__ v, float* __restrict__ u)
{
    int w = (blockIdx.x * 256 + threadIdx.x) >> 6;
    int lane = threadIdx.x & 63;
    if (w >= B_ * MP1) return;
    int b = w / MP1, i = w % MP1;
    const float* row = S + ((size_t)b * MP1 + i) * NP1;
    const float* vb = v + b * NP1;
    float sm = 0.f;
    #pragma unroll
    for (int q = 0; q < 17; ++q) {
        int j = lane + q * 64;
        if (j < NP1) sm += expf(row[j] + vb[j]);
    }
    #pragma unroll
    for (int o = 32; o; o >>= 1) sm += __shfl_xor(sm, o);
    if (lane == 0) {
        float la = (i == M_) ? LOG_HALF : LOG_NORM;
        u[b * MP1 + i] = la - logf(sm);
    }
}

__global__ __launch_bounds__(256) void col_pass1_kernel(
    const float* __restrict__ S, const float* __restrict__ u,
    float* __restrict__ pm, float* __restrict__ ps)
{
    int j = blockIdx.x * 256 + threadIdx.x;
    int b = blockIdx.z;
    int i0 = blockIdx.y * 128;
    int i1 = min(i0 + 128, MP1);
    if (j >= NP1) return;
    const float* p  = S + ((size_t)b * MP1 + i0) * NP1 + j;
    const float* ub = u + b * MP1;
    float sm = 0.f;
    for (int i = i0; i < i1; ++i) {
        sm += expf(*p + ub[i]);
        p += NP1;
    }
    int idx = (blockIdx.y * B_ + b) * NP1 + j;
    pm[idx] = 0.f;
    ps[idx] = sm;
}

__global__ __launch_bounds__(256) void col_pass2_kernel(
    const float* __restrict__ pm, const float* __restrict__ ps, float* __restrict__ v)
{
    int j = blockIdx.x * 256 + threadIdx.x;
    int b = blockIdx.y;
    if (j >= NP1) return;
    float Ssum = 0.f;
    #pragma unroll
    for (int c = 0; c < 9; ++c) Ssum += ps[(c * B_ + b) * NP1 + j];
    float lb = (j == N_) ? LOG_HALF : LOG_NORM;
    v[b * NP1 + j] = lb - logf(Ssum);
}

__global__ __launch_bounds__(256) void row_final_kernel(
    float* __restrict__ S, const float* __restrict__ v)
{
    int w = (blockIdx.x * 256 + threadIdx.x) >> 6;
    int lane = threadIdx.x & 63;
    if (w >= B_ * MP1) return;
    int b = w / MP1, i = w % MP1;
    float* row = S + ((size_t)b * MP1 + i) * NP1;
    const float* vb = v + b * NP1;
    float et[17];
    float sm = 0.f;
    #pragma unroll
    for (int q = 0; q < 17; ++q) {
        int j = lane + q * 64;
        float e = 0.f;
        if (j < NP1) e = expf(row[j] + vb[j]);
        et[q] = e;
        sm += e;
    }
    #pragma unroll
    for (int o = 32; o; o >>= 1) sm += __shfl_xor(sm, o);
    float A = (i == M_) ? 0.5f : (1.0f / 2048.0f);
    float scale = (A / sm) * 2048.0f;
    #pragma unroll
    for (int q = 0; q < 17; ++q) {
        int j = lane + q * 64;
        if (j < NP1) row[j] = et[q] * scale;
    }
}

__global__ __launch_bounds__(256) void zero_kernel(float* __restrict__ p, int n)
{
    int i = blockIdx.x * 256 + threadIdx.x;
    if (i < n) p[i] = 0.f;
}

extern "C" void kernel_launch(void* const* d_in, const int* in_sizes, int n_in,
                              void* d_out, int out_size, void* d_ws, size_t ws_size,
                              hipStream_t stream)
{
    const float* tf    = (const float*)d_in[0];
    const float* df    = (const float*)d_in[1];
    const float* tl    = (const float*)d_in[2];
    const float* dl    = (const float*)d_in[3];
    const float* alpha = (const float*)d_in[4];
    const float* eps   = (const float*)d_in[5];
    float* out = (float*)d_out;

    const size_t bf_one   = (size_t)B_ * M_ * D_ * 2;
    const size_t sh_bytes = (size_t)B_ * M_ * SSTR * 2;
    const size_t vf2      = 2 * (size_t)B_ * VSTR;          // v double buffer (floats)
    const size_t ps2      = 2 * (size_t)PSTOT;              // ps double buffer (floats)
    const size_t invs_f   = (size_t)B_ * M_ * 2;
    const size_t need_pre = 2 * bf_one + sh_bytes + (vf2 + ps2) * 4 + 512;
    const size_t need_mid = sh_bytes + (vf2 + ps2 + invs_f) * 4 + 512;

    if (ws_size >= need_pre) {
        unsigned short* tfh = (unsigned short*)d_ws;
        unsigned short* dfh = tfh + (size_t)B_ * M_ * D_;
        _Float16* Sh = (_Float16*)((char*)d_ws + 2 * bf_one);
        float* fbase = (float*)((char*)d_ws + ((2 * bf_one + sh_bytes + 255) & ~(size_t)255));
        float* vbuf  = fbase;
        float* psbuf = vbuf + vf2;

        norms_kernel_t<true><<<(B_ * 2048) / 4, 256, 0, stream>>>(tf, df, nullptr, nullptr, tfh, dfh);
        gemm_s_kernel<2><<<1024, 256, 0, stream>>>(tfh, dfh, tl, dl, nullptr, nullptr, eps, Sh);

        for (int it = 0; it < NUM_SINK; ++it)
            rowcolv64<<<256, 256, 0, stream>>>(Sh, vbuf, psbuf, alpha, eps, it);
        finalv<<<512 + B_, 256, 0, stream>>>(Sh, vbuf, psbuf, alpha, eps, out);
    } else if (ws_size >= need_mid) {
        _Float16* Sh = (_Float16*)d_ws;
        float* fbase = (float*)((char*)d_ws + ((sh_bytes + 255) & ~(size_t)255));
        float* inv1  = fbase;
        float* inv2  = inv1 + B_ * M_;
        float* vbuf  = inv2 + B_ * N_;
        float* psbuf = vbuf + vf2;

        norms_kernel_t<false><<<(B_ * 2048) / 4, 256, 0, stream>>>(tf, df, inv1, inv2, nullptr, nullptr);
        gemm_s_kernel<1><<<1024, 256, 0, stream>>>(tf, df, tl, dl, inv1, inv2, eps, Sh);

        for (int it = 0; it < NUM_SINK; ++it)
            rowcolv64<<<256, 256, 0, stream>>>(Sh, vbuf, psbuf, alpha, eps, it);
        finalv<<<512 + B_, 256, 0, stream>>>(Sh, vbuf, psbuf, alpha, eps, out);
    } else {
        float* S = out;
        float* ws = (float*)d_ws;
        float* inv1 = ws;
        float* inv2 = inv1 + B_ * M_;
        float* u    = inv2 + B_ * N_;
        float* v    = u + B_ * MP1;
        float* pm   = v + B_ * NP1;
        float* ps   = pm + 9 * B_ * NP1;

        zero_kernel<<<(B_ * NP1 + 255) / 256, 256, 0, stream>>>(v, B_ * NP1);
        norms_kernel_t<false><<<(B_ * 2048) / 4, 256, 0, stream>>>(tf, df, inv1, inv2, nullptr, nullptr);
        gemm_s_kernel<0><<<1024, 256, 0, stream>>>(tf, df, tl, dl, inv1, inv2, eps, S);
        fill_edges_f32<<<(B_ * (NP1 + M_) + 255) / 256, 256, 0, stream>>>(S, alpha, eps);

        int rowblocks = (B_ * MP1 + 3) / 4;
        for (int it = 0; it < NUM_SINK; ++it) {
            row_pass_kernel<<<rowblocks, 256, 0, stream>>>(S, v, u);
            col_pass1_kernel<<<dim3(5, 9, 16), 256, 0, stream>>>(S, u, pm, ps);
            col_pass2_kernel<<<dim3(5, 16), 256, 0, stream>>>(pm, ps, v);
        }
        row_final_kernel<<<rowblocks, 256, 0, stream>>>(S, v);
    }
}

// Round 12
// 145.308 us; speedup vs baseline: 1.1616x; 1.1616x over previous
//
#include <hip/hip_runtime.h>
#include <math.h>

#define B_ 16
#define M_ 1024
#define N_ 1024
#define D_ 512
#define MP1 1025
#define NP1 1025
#define NUM_SINK 8
#define BK 64
#define SSTR 1024        // fp8 S row stride (bytes) — interior only
#define VSTR 1028        // v stride (floats), 16B-aligned
#define NCHK 16          // ps chunks (64 rows each)
// log(1/2048), log(1/2)
#define LOG_NORM (-7.6246189861593985f)
#define LOG_HALF (-0.6931471805599453f)

typedef __attribute__((ext_vector_type(8))) short bf16x8;
typedef __attribute__((ext_vector_type(4))) float f32x4;
typedef __attribute__((ext_vector_type(2))) float f32x2;

__device__ inline short f2bf(float x) {
    unsigned u = __builtin_bit_cast(unsigned, x);
    u = (u + 0x7FFFu + ((u >> 16) & 1u)) >> 16;
    return (short)u;
}

// ---------------- fp8 e4m3 encode/decode (HW cvt on gfx950, sw fallback) ----------------
#if __has_builtin(__builtin_amdgcn_cvt_pk_fp8_f32) && __has_builtin(__builtin_amdgcn_cvt_pk_f32_fp8)
#define FP8_HW 1
#else
#define FP8_HW 0
#endif

__device__ inline unsigned char enc8(float x) {
#if FP8_HW
    return (unsigned char)(__builtin_amdgcn_cvt_pk_fp8_f32(x, x, 0, false) & 0xFF);
#else
    unsigned s = (__builtin_bit_cast(unsigned, x) >> 31) << 7;
    float ax = fminf(fabsf(x), 448.0f);
    unsigned bits;
    if (ax < 0.015625f) {
        bits = (unsigned)(ax * 512.0f + 0.5f);
        if (bits > 8) bits = 8;
    } else {
        int e; float m = frexpf(ax, &e);      // ax = m*2^e, m in [0.5,1)
        int k = e - 1;
        int j = (int)((m * 2.0f - 1.0f) * 8.0f + 0.5f);
        if (j == 8) { j = 0; k += 1; }
        if (k > 8) { k = 8; j = 7; }
        bits = ((unsigned)(k + 7) << 3) | (unsigned)j;
    }
    return (unsigned char)(s | bits);
#endif
}

__device__ inline void dec4(unsigned u, float* o) {
#if FP8_HW
    f32x2 a = __builtin_amdgcn_cvt_pk_f32_fp8((int)u, false);
    f32x2 b = __builtin_amdgcn_cvt_pk_f32_fp8((int)u, true);
    o[0] = a[0]; o[1] = a[1]; o[2] = b[0]; o[3] = b[1];
#else
    #pragma unroll
    for (int i = 0; i < 4; ++i) {
        unsigned bt = (u >> (8 * i)) & 0xFF;
        unsigned s = bt >> 7, em = bt & 0x7F;
        float mag;
        if (em >= 0x08) {
            unsigned fb = (((em >> 3) + 120) << 23) | ((em & 7) << 20);
            mag = __builtin_bit_cast(float, fb);
        } else {
            mag = (float)em * 0.001953125f;
        }
        o[i] = s ? -mag : mag;
    }
#endif
}

__device__ inline void gload16(const void* g, void* l) {
    __builtin_amdgcn_global_load_lds(
        (const __attribute__((address_space(1))) unsigned int*)g,
        (__attribute__((address_space(3))) unsigned int*)l, 16, 0, 0);
}

// ---------------- norms (+init of v/sums in block 0): one wave per feature row ----------------
template<bool PRE>
__global__ __launch_bounds__(256) void norms_kernel_t(
    const float* __restrict__ tf, const float* __restrict__ df,
    float* __restrict__ inv1, float* __restrict__ inv2,
    unsigned short* __restrict__ tfh, unsigned short* __restrict__ dfh,
    float* __restrict__ v, float* __restrict__ sums_p)
{
    if (PRE && blockIdx.x == 0) {
        const int nv = B_ * VSTR, ns = 2 * B_ * 17;
        for (int t = threadIdx.x; t < nv + ns; t += 256) {
            if (t < nv) v[t] = 0.f;
            else {
                int u2 = t - nv;
                int p = u2 / (B_ * 17), s = u2 % 17;
                sums_p[u2] = (p == 0 && s == 0) ? 1025.0f : 0.f;
            }
        }
    }
    int w = (blockIdx.x * 256 + threadIdx.x) >> 6;
    int lane = threadIdx.x & 63;
    if (w >= B_ * 2048) return;
    int b = w >> 11;
    int rr = w & 2047;
    const float* src;
    float* dst = nullptr;
    unsigned short* dsth = nullptr;
    if (rr < M_) { src = tf + ((size_t)b * M_ + rr) * D_;
                   if (!PRE) dst = inv1 + b * M_ + rr;
                   if (PRE)  dsth = tfh + ((size_t)b * M_ + rr) * D_; }
    else         { src = df + ((size_t)b * N_ + (rr - M_)) * D_;
                   if (!PRE) dst = inv2 + b * N_ + (rr - M_);
                   if (PRE)  dsth = dfh + ((size_t)b * N_ + (rr - M_)) * D_; }
    float4 x = *(const float4*)(src + lane * 4);
    float4 y = *(const float4*)(src + 256 + lane * 4);
    float ss = x.x*x.x + x.y*x.y + x.z*x.z + x.w*x.w
             + y.x*y.x + y.y*y.y + y.z*y.z + y.w*y.w;
    #pragma unroll
    for (int o = 32; o; o >>= 1) ss += __shfl_xor(ss, o);
    if (PRE) {
        float rn = rsqrtf(ss);
        ushort4 hx, hy;
        hx.x = (unsigned short)f2bf(x.x*rn); hx.y = (unsigned short)f2bf(x.y*rn);
        hx.z = (unsigned short)f2bf(x.z*rn); hx.w = (unsigned short)f2bf(x.w*rn);
        hy.x = (unsigned short)f2bf(y.x*rn); hy.y = (unsigned short)f2bf(y.y*rn);
        hy.z = (unsigned short)f2bf(y.z*rn); hy.w = (unsigned short)f2bf(y.w*rn);
        *(ushort4*)(dsth + lane * 4) = hx;
        *(ushort4*)(dsth + 256 + lane * 4) = hy;
    } else {
        if (lane == 0) *dst = 1.0f / sqrtf(ss);
    }
}

// ---------------- MFMA GEMM + epilogue: S = (cos*mask - 1)/lambda ----------------
// MODE 0: fp32 out (NP1 stride). MODE 1: fp8 out, f2bf staging.
// MODE 2: fp8 out, global_load_lds from PRESCALED bf16, double-buffered.
template<int MODE>
__global__ __launch_bounds__(256) void gemm_s_kernel(
    const void* __restrict__ A, const void* __restrict__ Bm,
    const float* __restrict__ tl, const float* __restrict__ dl,
    const float* __restrict__ inv1, const float* __restrict__ inv2,
    const float* __restrict__ eps_p, void* __restrict__ Sout)
{
    __shared__ __align__(16) unsigned short As[2][128 * BK];
    __shared__ __align__(16) unsigned short Bs[2][128 * BK];

    int flat = blockIdx.x;
    int swz = (flat & 7) * 128 + (flat >> 3);
    int jb = swz & 7, ib = (swz >> 3) & 7;
    int b  = swz >> 6;
    int i0 = ib * 128;
    int j0 = jb * 128;

    int tid  = threadIdx.x;
    int lane = tid & 63;
    int w    = tid >> 6;
    int wm   = w >> 1, wn = w & 1;

    f32x4 acc[4][4] = {};

    if constexpr (MODE == 2) {
        const unsigned short* Ah = (const unsigned short*)A  + (size_t)b * M_ * D_;
        const unsigned short* Bh = (const unsigned short*)Bm + (size_t)b * N_ * D_;
        int gcol = ((lane & 7) ^ (lane >> 3)) << 3;
        int rloc = lane >> 3;

        auto stage = [&](int k0, int buf) {
            #pragma unroll
            for (int c = 0; c < 4; ++c) {
                int r = (w * 4 + c) * 8 + rloc;
                gload16(Ah + (size_t)(i0 + r) * D_ + k0 + gcol,
                        (char*)As[buf] + (w * 4 + c) * 1024 + lane * 16);
                gload16(Bh + (size_t)(j0 + r) * D_ + k0 + gcol,
                        (char*)Bs[buf] + (w * 4 + c) * 1024 + lane * 16);
            }
        };

        stage(0, 0);
        __syncthreads();
        int cur = 0;
        for (int t = 0; t < D_ / BK; ++t) {
            if (t < D_ / BK - 1) stage((t + 1) * BK, cur ^ 1);
            #pragma unroll
            for (int ks = 0; ks < 2; ++ks) {
                int kb = ks * 64 + ((lane >> 4) << 4);
                bf16x8 af[4], bfr[4];
                #pragma unroll
                for (int m = 0; m < 4; ++m) {
                    int ra = wm * 64 + m * 16 + (lane & 15);
                    af[m] = *(const bf16x8*)((const char*)As[cur] + ra * 128 + (kb ^ ((ra & 7) << 4)));
                    int rb = wn * 64 + m * 16 + (lane & 15);
                    bfr[m] = *(const bf16x8*)((const char*)Bs[cur] + rb * 128 + (kb ^ ((rb & 7) << 4)));
                }
                #pragma unroll
                for (int m = 0; m < 4; ++m)
                    #pragma unroll
                    for (int n = 0; n < 4; ++n)
                        acc[m][n] = __builtin_amdgcn_mfma_f32_16x16x32_bf16(af[m], bfr[n], acc[m][n], 0, 0, 0);
            }
            __syncthreads();
            cur ^= 1;
        }
    } else {
        const float* Ab = (const float*)A  + (size_t)b * M_ * D_;
        const float* Bb = (const float*)Bm + (size_t)b * N_ * D_;
        int seg   = tid & 7;
        int rbase = tid >> 3;
        for (int k0 = 0; k0 < D_; k0 += BK) {
            #pragma unroll
            for (int rr = 0; rr < 4; ++rr) {
                int r = rbase + rr * 32;
                int colx = (seg * 16) ^ ((r & 7) << 4);
                {
                    const float* pa = Ab + (size_t)(i0 + r) * D_ + k0 + seg * 8;
                    float4 a0 = *(const float4*)pa;
                    float4 a1 = *(const float4*)(pa + 4);
                    bf16x8 hv;
                    hv[0] = f2bf(a0.x); hv[1] = f2bf(a0.y); hv[2] = f2bf(a0.z); hv[3] = f2bf(a0.w);
                    hv[4] = f2bf(a1.x); hv[5] = f2bf(a1.y); hv[6] = f2bf(a1.z); hv[7] = f2bf(a1.w);
                    *(bf16x8*)((char*)As[0] + r * 128 + colx) = hv;
                }
                {
                    const float* pb = Bb + (size_t)(j0 + r) * D_ + k0 + seg * 8;
                    float4 b0 = *(const float4*)pb;
                    float4 b1 = *(const float4*)(pb + 4);
                    bf16x8 hv;
                    hv[0] = f2bf(b0.x); hv[1] = f2bf(b0.y); hv[2] = f2bf(b0.z); hv[3] = f2bf(b0.w);
                    hv[4] = f2bf(b1.x); hv[5] = f2bf(b1.y); hv[6] = f2bf(b1.z); hv[7] = f2bf(b1.w);
                    *(bf16x8*)((char*)Bs[0] + r * 128 + colx) = hv;
                }
            }
            __syncthreads();
            #pragma unroll
            for (int ks = 0; ks < 2; ++ks) {
                int kb = ks * 64 + ((lane >> 4) << 4);
                bf16x8 af[4], bfr[4];
                #pragma unroll
                for (int m = 0; m < 4; ++m) {
                    int ra = wm * 64 + m * 16 + (lane & 15);
                    af[m] = *(const bf16x8*)((const char*)As[0] + ra * 128 + (kb ^ ((ra & 7) << 4)));
                    int rb = wn * 64 + m * 16 + (lane & 15);
                    bfr[m] = *(const bf16x8*)((const char*)Bs[0] + rb * 128 + (kb ^ ((rb & 7) << 4)));
                }
                #pragma unroll
                for (int m = 0; m < 4; ++m)
                    #pragma unroll
                    for (int n = 0; n < 4; ++n)
                        acc[m][n] = __builtin_amdgcn_mfma_f32_16x16x32_bf16(af[m], bfr[n], acc[m][n], 0, 0, 0);
            }
            __syncthreads();
        }
    }

    float lam = __expf(eps_p[0]) + 0.03f;
    float inv_lam = 1.0f / lam;
    int crow0 = i0 + wm * 64;
    int ccol0 = j0 + wn * 64;
    int rlane = lane >> 4;
    int clane = lane & 15;

    float invb_[4], dlx_[4], dly_[4];
    #pragma unroll
    for (int n = 0; n < 4; ++n) {
        int j = ccol0 + n * 16 + clane;
        if (MODE != 2) invb_[n] = inv2[b * N_ + j];
        dlx_[n]  = dl[((size_t)b * N_ + j) * 2 + 0];
        dly_[n]  = dl[((size_t)b * N_ + j) * 2 + 1];
    }
    #pragma unroll
    for (int m = 0; m < 4; ++m) {
        #pragma unroll
        for (int reg = 0; reg < 4; ++reg) {
            int i = crow0 + m * 16 + rlane * 4 + reg;
            float inva = (MODE != 2) ? inv1[b * M_ + i] : 1.0f;
            float tlx  = tl[((size_t)b * M_ + i) * 2 + 0];
            float tly  = tl[((size_t)b * M_ + i) * 2 + 1];
            #pragma unroll
            for (int n = 0; n < 4; ++n) {
                float cosv = (MODE == 2) ? acc[m][n][reg]
                                         : acc[m][n][reg] * inva * invb_[n];
                float dx = tlx - dlx_[n];
                float dy = tly - dly_[n];
                float mi = (fmaf(dx, dx, dy * dy) <= 0.09f) ? inv_lam : 0.0f;
                float val = fmaf(cosv, mi, -inv_lam);
                int col = ccol0 + n * 16 + clane;
                if (MODE >= 1) {
                    unsigned char* Srow = (unsigned char*)Sout + ((size_t)b * M_ + i) * SSTR;
                    Srow[col] = enc8(val);
                } else {
                    float* Srow = (float*)Sout + ((size_t)b * MP1 + i) * NP1;
                    Srow[col] = val;
                }
            }
        }
    }
}

// ---------------- init (tier2): zero v + init sums_p ping-pong ----------------
__global__ __launch_bounds__(256) void init_hv(
    float* __restrict__ v, float* __restrict__ sums_p)
{
    int t = blockIdx.x * 256 + threadIdx.x;
    if (t < B_ * VSTR) v[t] = 0.f;
    int u2 = t - B_ * VSTR;
    if (u2 >= 0 && u2 < 2 * B_ * 17) {
        int p = u2 / (B_ * 17), s = u2 % 17;
        sums_p[u2] = (p == 0 && s == 0) ? 1025.0f : 0.f;
    }
}

// ================= fp8 path: fused row-update + column partials =================
// 64 rows/block (4 waves x 16 rows, ALL preloaded). 256 blocks = 1/CU.
__global__ __launch_bounds__(256, 1) void rowcol64(
    const unsigned char* __restrict__ Sh, const float* __restrict__ v,
    float* __restrict__ ps,
    const float* __restrict__ alpha_p, const float* __restrict__ eps_p)
{
    int blk = blockIdx.x;           // 0..255
    int b = blk >> 4, k = blk & 15;
    int tid = threadIdx.x, lane = tid & 63, w = tid >> 6;

    __shared__ float red[4][64][17];   // stride-17 words: conflict-free

    const float* vb = v + (size_t)b * VSTR;
    float vreg[16];
    {
        float4 v0 = *(const float4*)(vb + lane * 8);
        float4 v1 = *(const float4*)(vb + lane * 8 + 4);
        float4 v2 = *(const float4*)(vb + 512 + lane * 8);
        float4 v3 = *(const float4*)(vb + 512 + lane * 8 + 4);
        vreg[0]=v0.x; vreg[1]=v0.y; vreg[2]=v0.z; vreg[3]=v0.w;
        vreg[4]=v1.x; vreg[5]=v1.y; vreg[6]=v1.z; vreg[7]=v1.w;
        vreg[8]=v2.x; vreg[9]=v2.y; vreg[10]=v2.z; vreg[11]=v2.w;
        vreg[12]=v3.x; vreg[13]=v3.y; vreg[14]=v3.z; vreg[15]=v3.w;
    }
    float lam = __expf(eps_p[0]) + 0.03f;
    float s_a = (alpha_p[0] - 1.0f) / lam;
    float et16c = __expf(s_a + vb[1024]);

    const unsigned char* Sb = Sh + ((size_t)b << 20);
    int rbase = k * 64 + w * 16;

    // preload all 16 rows as fp8 (32 independent 8B loads in flight)
    uint2 g0[16], g1[16];
    #pragma unroll
    for (int rr = 0; rr < 16; ++rr) {
        const unsigned char* row = Sb + (size_t)(rbase + rr) * SSTR;
        g0[rr] = *(const uint2*)(row + lane * 8);
        g1[rr] = *(const uint2*)(row + 512 + lane * 8);
    }

    float creg[16] = {};
    float sum_scale = 0.f;

    #pragma unroll
    for (int rr = 0; rr < 16; ++rr) {
        float d0[8], d1[8];
        dec4(g0[rr].x, d0); dec4(g0[rr].y, d0 + 4);
        dec4(g1[rr].x, d1); dec4(g1[rr].y, d1 + 4);
        float et[16];
        float rs = 0.f;
        #pragma unroll
        for (int e = 0; e < 8; ++e) { et[e] = __expf(d0[e] + vreg[e]); rs += et[e]; }
        #pragma unroll
        for (int e = 0; e < 8; ++e) { et[8+e] = __expf(d1[e] + vreg[8+e]); rs += et[8+e]; }
        #pragma unroll
        for (int o = 32; o; o >>= 1) rs += __shfl_xor(rs, o);
        rs += et16c;                                   // dustbin column term
        float scale = (1.0f / 2048.0f) / rs;           // exp(u_i)
        #pragma unroll
        for (int e = 0; e < 16; ++e) creg[e] += et[e] * scale;
        sum_scale += scale;
    }

    #pragma unroll
    for (int e = 0; e < 16; ++e) red[w][lane][e] = creg[e];
    if (lane == 0) red[w][0][16] = sum_scale;
    __syncthreads();

    float* pso = ps + (size_t)(k * 16 + b) * 1025;
    for (int j = tid; j < 1024; j += 256) {
        int lane_j = (j & 511) >> 3;
        int e_j    = ((j >> 9) << 3) | (j & 7);
        pso[j] = red[0][lane_j][e_j] + red[1][lane_j][e_j]
               + red[2][lane_j][e_j] + red[3][lane_j][e_j];
    }
    if (tid == 0)
        pso[1024] = et16c * (red[0][0][16] + red[1][0][16] + red[2][0][16] + red[3][0][16]);
}

// col update: one wave per (b, 64-col segment). 272 waves = 68 blocks.
__global__ __launch_bounds__(256) void colpass32(
    const float* __restrict__ ps, float* __restrict__ v,
    float* __restrict__ sums_p, int it)
{
    int gw = blockIdx.x * 4 + (threadIdx.x >> 6);
    int lane = threadIdx.x & 63;
    if (gw >= B_ * 17) return;
    int b = gw / 17, seg = gw % 17;
    int j = seg * 64 + lane;
    int par = it & 1;
    float sum_old = 0.f;
    #pragma unroll
    for (int s = 0; s < 17; ++s) sum_old += sums_p[par * (B_ * 17) + b * 17 + s];
    float ev = 0.f;
    if (j <= 1024) {
        size_t vidx = (size_t)b * VSTR + j;
        float vj = v[vidx];
        const float* pp = ps + (size_t)b * 1025 + j;
        float cs = 0.f;
        #pragma unroll
        for (int c = 0; c < NCHK; ++c) cs += pp[(size_t)c * (16 * 1025)];
        cs += 0.5f * __expf(vj) / sum_old;
        float lb = (j == 1024) ? LOG_HALF : LOG_NORM;
        float vn = vj + lb - __logf(cs);
        v[vidx] = vn;
        ev = __expf(vn);
    }
    #pragma unroll
    for (int o = 32; o; o >>= 1) ev += __shfl_xor(ev, o);
    if (lane == 0) sums_p[(par ^ 1) * (B_ * 17) + b * 17 + seg] = ev;
}

// final: blocks <512 write interior rows (+dustbin col); blocks >=512 write dustbin row
__global__ __launch_bounds__(256) void final32(
    const unsigned char* __restrict__ Sh, const float* __restrict__ v,
    const float* __restrict__ sums_p,
    const float* __restrict__ alpha_p, const float* __restrict__ eps_p,
    float* __restrict__ out)
{
    int blk = blockIdx.x;
    int tid = threadIdx.x, lane = tid & 63, w = tid >> 6;

    if (blk >= 512) {
        int gw = (blk - 512) * 4 + w;
        if (gw >= B_ * 17) return;
        int b = gw / 17, seg = gw % 17, j = seg * 64 + lane;
        if (j > 1024) return;
        float sumv = 0.f;
        int par = NUM_SINK & 1;
        #pragma unroll
        for (int s = 0; s < 17; ++s) sumv += sums_p[par * (B_ * 17) + b * 17 + s];
        out[((size_t)b * MP1 + 1024) * NP1 + j] = __expf(v[(size_t)b * VSTR + j]) * 1024.0f / sumv;
        return;
    }

    int b = blk >> 5, k = blk & 31;
    const float* vb = v + (size_t)b * VSTR;
    float vreg[16];
    {
        float4 v0 = *(const float4*)(vb + lane * 8);
        float4 v1 = *(const float4*)(vb + lane * 8 + 4);
        float4 v2 = *(const float4*)(vb + 512 + lane * 8);
        float4 v3 = *(const float4*)(vb + 512 + lane * 8 + 4);
        vreg[0]=v0.x; vreg[1]=v0.y; vreg[2]=v0.z; vreg[3]=v0.w;
        vreg[4]=v1.x; vreg[5]=v1.y; vreg[6]=v1.z; vreg[7]=v1.w;
        vreg[8]=v2.x; vreg[9]=v2.y; vreg[10]=v2.z; vreg[11]=v2.w;
        vreg[12]=v3.x; vreg[13]=v3.y; vreg[14]=v3.z; vreg[15]=v3.w;
    }
    float lam = __expf(eps_p[0]) + 0.03f;
    float s_a = (alpha_p[0] - 1.0f) / lam;
    float et16c = __expf(s_a + vb[1024]);

    const unsigned char* Sb = Sh + ((size_t)b << 20);
    int rbase = k * 32 + w * 8;

    #pragma unroll
    for (int g = 0; g < 2; ++g) {
        uint2 g0[4], g1[4];
        #pragma unroll
        for (int rr = 0; rr < 4; ++rr) {
            const unsigned char* row = Sb + (size_t)(rbase + g * 4 + rr) * SSTR;
            g0[rr] = *(const uint2*)(row + lane * 8);
            g1[rr] = *(const uint2*)(row + 512 + lane * 8);
        }
        #pragma unroll
        for (int rr = 0; rr < 4; ++rr) {
            int r = rbase + g * 4 + rr;
            float d0[8], d1[8];
            dec4(g0[rr].x, d0); dec4(g0[rr].y, d0 + 4);
            dec4(g1[rr].x, d1); dec4(g1[rr].y, d1 + 4);
            float et[16];
            float rs = 0.f;
            #pragma unroll
            for (int e = 0; e < 8; ++e) { et[e] = __expf(d0[e] + vreg[e]); rs += et[e]; }
            #pragma unroll
            for (int e = 0; e < 8; ++e) { et[8+e] = __expf(d1[e] + vreg[8+e]); rs += et[8+e]; }
            #pragma unroll
            for (int o = 32; o; o >>= 1) rs += __shfl_xor(rs, o);
            rs += et16c;
            float sc = 1.0f / rs;   // = exp(u)*2048
            float* orow = out + ((size_t)b * MP1 + r) * NP1;
            float4 o0 = {et[0]*sc,  et[1]*sc,  et[2]*sc,  et[3]*sc};
            float4 o1 = {et[4]*sc,  et[5]*sc,  et[6]*sc,  et[7]*sc};
            float4 o2 = {et[8]*sc,  et[9]*sc,  et[10]*sc, et[11]*sc};
            float4 o3 = {et[12]*sc, et[13]*sc, et[14]*sc, et[15]*sc};
            *(float4*)(orow + lane * 8)           = o0;
            *(float4*)(orow + lane * 8 + 4)       = o1;
            *(float4*)(orow + 512 + lane * 8)     = o2;
            *(float4*)(orow + 512 + lane * 8 + 4) = o3;
            if (lane == 0) orow[1024] = et16c * sc;
        }
    }
}

// ================= fp32 fallback kernels (tier 3, S in d_out) =================

__global__ __launch_bounds__(256) void fill_edges_f32(
    float* __restrict__ Sout, const float* __restrict__ alpha_p, const float* __restrict__ eps_p)
{
    int t = blockIdx.x * 256 + threadIdx.x;
    if (t >= B_ * (NP1 + M_)) return;
    int b = t / (NP1 + M_), r = t % (NP1 + M_);
    float lam = expf(eps_p[0]) + 0.03f;
    float s = (alpha_p[0] - 1.0f) / lam;
    size_t idx;
    if (r < NP1) idx = ((size_t)b * MP1 + M_) * NP1 + r;
    else         idx = ((size_t)b * MP1 + (r - NP1)) * NP1 + N_;
    Sout[idx] = s;
}

__global__ __launch_bounds__(256) void row_pass_kernel(
    const float* __restrict__ S, const float* __restrict__ v, float* __restrict__ u)
{
    int w = (blockIdx.x * 256 + threadIdx.x) >> 6;
    int lane = threadIdx.x & 63;
    if (w >= B_ * MP1) return;
    int b = w / MP1, i = w % MP1;
    const float* row = S + ((size_t)b * MP1 + i) * NP1;
    const float* vb = v + b * NP1;
    float sm = 0.f;
    #pragma unroll
    for (int q = 0; q < 17; ++q) {
        int j = lane + q * 64;
        if (j < NP1) sm += expf(row[j] + vb[j]);
    }
    #pragma unroll
    for (int o = 32; o; o >>= 1) sm += __shfl_xor(sm, o);
    if (lane == 0) {
        float la = (i == M_) ? LOG_HALF : LOG_NORM;
        u[b * MP1 + i] = la - logf(sm);
    }
}

__global__ __launch_bounds__(256) void col_pass1_kernel(
    const float* __restrict__ S, const float* __restrict__ u,
    float* __restrict__ pm, float* __restrict__ ps)
{
    int j = blockIdx.x * 256 + threadIdx.x;
    int b = blockIdx.z;
    int i0 = blockIdx.y * 128;
    int i1 = min(i0 + 128, MP1);
    if (j >= NP1) return;
    const float* p  = S + ((size_t)b * MP1 + i0) * NP1 + j;
    const float* ub = u + b * MP1;
    float sm = 0.f;
    for (int i = i0; i < i1; ++i) {
        sm += expf(*p + ub[i]);
        p += NP1;
    }
    int idx = (blockIdx.y * B_ + b) * NP1 + j;
    pm[idx] = 0.f;
    ps[idx] = sm;
}

__global__ __launch_bounds__(256) void col_pass2_kernel(
    const float* __restrict__ pm, const float* __restrict__ ps, float* __restrict__ v)
{
    int j = blockIdx.x * 256 + threadIdx.x;
    int b = blockIdx.y;
    if (j >= NP1) return;
    float Ssum = 0.f;
    #pragma unroll
    for (int c = 0; c < 9; ++c) Ssum += ps[(c * B_ + b) * NP1 + j];
    float lb = (j == N_) ? LOG_HALF : LOG_NORM;
    v[b * NP1 + j] = lb - logf(Ssum);
}

__global__ __launch_bounds__(256) void row_final_kernel(
    float* __restrict__ S, const float* __restrict__ v)
{
    int w = (blockIdx.x * 256 + threadIdx.x) >> 6;
    int lane = threadIdx.x & 63;
    if (w >= B_ * MP1) return;
    int b = w / MP1, i = w % MP1;
    float* row = S + ((size_t)b * MP1 + i) * NP1;
    const float* vb = v + b * NP1;
    float et[17];
    float sm = 0.f;
    #pragma unroll
    for (int q = 0; q < 17; ++q) {
        int j = lane + q * 64;
        float e = 0.f;
        if (j < NP1) e = expf(row[j] + vb[j]);
        et[q] = e;
        sm += e;
    }
    #pragma unroll
    for (int o = 32; o; o >>= 1) sm += __shfl_xor(sm, o);
    float A = (i == M_) ? 0.5f : (1.0f / 2048.0f);
    float scale = (A / sm) * 2048.0f;
    #pragma unroll
    for (int q = 0; q < 17; ++q) {
        int j = lane + q * 64;
        if (j < NP1) row[j] = et[q] * scale;
    }
}

__global__ __launch_bounds__(256) void zero_kernel(float* __restrict__ p, int n)
{
    int i = blockIdx.x * 256 + threadIdx.x;
    if (i < n) p[i] = 0.f;
}

extern "C" void kernel_launch(void* const* d_in, const int* in_sizes, int n_in,
                              void* d_out, int out_size, void* d_ws, size_t ws_size,
                              hipStream_t stream)
{
    const float* tf    = (const float*)d_in[0];
    const float* df    = (const float*)d_in[1];
    const float* tl    = (const float*)d_in[2];
    const float* dl    = (const float*)d_in[3];
    const float* alpha = (const float*)d_in[4];
    const float* eps   = (const float*)d_in[5];
    float* out = (float*)d_out;

    const size_t bf_one   = (size_t)B_ * M_ * D_ * 2;
    const size_t sh_bytes = (size_t)B_ * M_ * SSTR;     // fp8 S: 16.8 MB
    const size_t vf       = (size_t)B_ * VSTR;
    const size_t sums_f   = 2 * B_ * 17;
    const size_t invs_f   = (size_t)B_ * M_ * 2;
    const size_t need_pre = 2 * bf_one + sh_bytes + (vf + sums_f) * 4 + 512;
    const size_t need_mid = sh_bytes + (vf + sums_f + invs_f) * 4 + 512;

    int initblocks = (int)((vf + sums_f + 255) / 256);

    if (ws_size >= need_pre) {
        unsigned short* tfh = (unsigned short*)d_ws;
        unsigned short* dfh = tfh + (size_t)B_ * M_ * D_;
        unsigned char* Sh = (unsigned char*)d_ws + 2 * bf_one;
        float* fbase = (float*)((char*)d_ws + ((2 * bf_one + sh_bytes + 255) & ~(size_t)255));
        float* v      = fbase;
        float* sums_p = v + vf;
        float* ps     = out;

        norms_kernel_t<true><<<(B_ * 2048) / 4, 256, 0, stream>>>(tf, df, nullptr, nullptr, tfh, dfh, v, sums_p);
        gemm_s_kernel<2><<<1024, 256, 0, stream>>>(tfh, dfh, tl, dl, nullptr, nullptr, eps, Sh);

        for (int it = 0; it < NUM_SINK; ++it) {
            rowcol64<<<256, 256, 0, stream>>>(Sh, v, ps, alpha, eps);
            colpass32<<<68, 256, 0, stream>>>(ps, v, sums_p, it);
        }
        final32<<<580, 256, 0, stream>>>(Sh, v, sums_p, alpha, eps, out);
    } else if (ws_size >= need_mid) {
        unsigned char* Sh = (unsigned char*)d_ws;
        float* fbase = (float*)((char*)d_ws + ((sh_bytes + 255) & ~(size_t)255));
        float* inv1   = fbase;
        float* inv2   = inv1 + B_ * M_;
        float* v      = inv2 + B_ * N_;
        float* sums_p = v + vf;
        float* ps     = out;

        init_hv<<<initblocks, 256, 0, stream>>>(v, sums_p);
        norms_kernel_t<false><<<(B_ * 2048) / 4, 256, 0, stream>>>(tf, df, inv1, inv2, nullptr, nullptr, nullptr, nullptr);
        gemm_s_kernel<1><<<1024, 256, 0, stream>>>(tf, df, tl, dl, inv1, inv2, eps, Sh);

        for (int it = 0; it < NUM_SINK; ++it) {
            rowcol64<<<256, 256, 0, stream>>>(Sh, v, ps, alpha, eps);
            colpass32<<<68, 256, 0, stream>>>(ps, v, sums_p, it);
        }
        final32<<<580, 256, 0, stream>>>(Sh, v, sums_p, alpha, eps, out);
    } else {
        float* S = out;
        float* ws = (float*)d_ws;
        float* inv1 = ws;
        float* inv2 = inv1 + B_ * M_;
        float* u    = inv2 + B_ * N_;
        float* v    = u + B_ * MP1;
        float* pm   = v + B_ * NP1;
        float* ps   = pm + 9 * B_ * NP1;

        zero_kernel<<<(B_ * NP1 + 255) / 256, 256, 0, stream>>>(v, B_ * NP1);
        norms_kernel_t<false><<<(B_ * 2048) / 4, 256, 0, stream>>>(tf, df, inv1, inv2, nullptr, nullptr, nullptr, nullptr);
        gemm_s_kernel<0><<<1024, 256, 0, stream>>>(tf, df, tl, dl, inv1, inv2, eps, S);
        fill_edges_f32<<<(B_ * (NP1 + M_) + 255) / 256, 256, 0, stream>>>(S, alpha, eps);

        int rowblocks = (B_ * MP1 + 3) / 4;
        for (int it = 0; it < NUM_SINK; ++it) {
            row_pass_kernel<<<rowblocks, 256, 0, stream>>>(S, v, u);
            col_pass1_kernel<<<dim3(5, 9, 16), 256, 0, stream>>>(S, u, pm, ps);
            col_pass2_kernel<<<dim3(5, 16), 256, 0, stream>>>(pm, ps, v);
        }
        row_final_kernel<<<rowblocks, 256, 0, stream>>>(S, v);
    }
}